// Round 1
// baseline (467.253 us; speedup 1.0000x reference)
//
#include <hip/hip_runtime.h>

#define N_NODES 100000
#define E_EDGES 1600000
#define IN_DIM  256
#define OUT_DIM 64
#define SLOPE   0.1f

// ---------------- K0: zero histogram ----------------
__global__ void zero_kernel(int* __restrict__ cnt, int n) {
  int i = blockIdx.x * blockDim.x + threadIdx.x;
  if (i < n) cnt[i] = 0;
}

// ---------------- K-detect: int32 vs int64 edge layout ----------------
// int64 little-endian => odd int32 slots (high words) are all zero.
__global__ void detect_kernel(const int* __restrict__ edges, int* __restrict__ flag) {
  if (threadIdx.x == 0 && blockIdx.x == 0) {
    int all0 = 1;
    for (int j = 0; j < 64; ++j)
      if (edges[2 * j + 1] != 0) all0 = 0;
    *flag = all0;  // 1 => int64 layout, 0 => int32 layout
  }
}

__device__ __forceinline__ void load_edge(const int* __restrict__ edges, int e, int is64,
                                          int& s, int& d) {
  if (is64) { s = edges[4 * e];     d = edges[4 * e + 2]; }
  else      { s = edges[2 * e];     d = edges[2 * e + 1]; }
}

// ---------------- K1: emb = X@W^T + b ; s1 = emb@a1 ; s2 = emb@a2 ----------------
__global__ __launch_bounds__(256) void embed_kernel(
    const float* __restrict__ features, const float* __restrict__ W,
    const float* __restrict__ bias, const float* __restrict__ a,
    float* __restrict__ emb, float* __restrict__ s1, float* __restrict__ s2)
{
  // W transposed+interleaved: wt4[(k>>2)*256 + l*4 + (k&3)] = W[l*256+k]
  // -> per k4, lane l reads a contiguous float4 (conflict-free ds_read_b128)
  __shared__ __align__(16) float wt4[(IN_DIM / 4) * OUT_DIM * 4];   // 64 KB
  __shared__ __align__(16) float fbuf[4][4][IN_DIM];                // 16 KB
  const int t = threadIdx.x;
  const int lane = t & 63;
  const int wv = t >> 6;

  for (int j = t; j < OUT_DIM * IN_DIM; j += 256) {
    int l = j >> 8;
    int k = j & 255;
    wt4[(k >> 2) * (OUT_DIM * 4) + l * 4 + (k & 3)] = W[j];
  }
  const float bl  = bias[lane];
  const float a1l = a[lane];
  const float a2l = a[OUT_DIM + lane];
  __syncthreads();

  const int base = blockIdx.x * 64;
  for (int pass = 0; pass < 4; ++pass) {
    const int r0 = base + pass * 16 + wv * 4;   // 4 rows per wave per pass
    #pragma unroll
    for (int r = 0; r < 4; ++r) {
      int row = r0 + r;
      float4 fv = make_float4(0.f, 0.f, 0.f, 0.f);
      if (row < N_NODES)
        fv = *(const float4*)&features[(size_t)row * IN_DIM + lane * 4];
      *(float4*)&fbuf[wv][r][lane * 4] = fv;
    }
    __syncthreads();  // ensure ds_writes landed (also cheap cross-wave sync)

    float acc[4] = {bl, bl, bl, bl};
    #pragma unroll 8
    for (int k4 = 0; k4 < IN_DIM / 4; ++k4) {
      const float4 w4 = *(const float4*)&wt4[k4 * (OUT_DIM * 4) + lane * 4];
      #pragma unroll
      for (int r = 0; r < 4; ++r) {
        const float4 fr = *(const float4*)&fbuf[wv][r][k4 * 4];  // broadcast read
        acc[r] += fr.x * w4.x + fr.y * w4.y + fr.z * w4.z + fr.w * w4.w;
      }
    }
    #pragma unroll
    for (int r = 0; r < 4; ++r) {
      int row = r0 + r;
      if (row < N_NODES) {   // wave-uniform guard (row depends only on wave id)
        float e = acc[r];
        emb[(size_t)row * OUT_DIM + lane] = e;
        float p1 = e * a1l;
        float p2 = e * a2l;
        #pragma unroll
        for (int o = 32; o > 0; o >>= 1) {
          p1 += __shfl_xor(p1, o, 64);
          p2 += __shfl_xor(p2, o, 64);
        }
        if (lane == 0) { s1[row] = p1; s2[row] = p2; }
      }
    }
    __syncthreads();
  }
}

// ---------------- K2: histogram of src ----------------
__global__ void hist_kernel(const int* __restrict__ edges, int* __restrict__ cnt,
                            const int* __restrict__ flag) {
  int e = blockIdx.x * blockDim.x + threadIdx.x;
  if (e < E_EDGES) {
    int s, d;
    load_edge(edges, e, *flag, s, d);
    atomicAdd(&cnt[s], 1);
  }
}

// ---------------- K3a: per-1024-chunk sums ----------------
__global__ __launch_bounds__(256) void chunk_reduce_kernel(const int* __restrict__ cnt,
                                                           int* __restrict__ bsum) {
  __shared__ int red[256];
  int b = blockIdx.x, t = threadIdx.x;
  int base = b * 1024;
  int s = 0;
  for (int j = t; j < 1024; j += 256) {
    int i = base + j;
    if (i < N_NODES) s += cnt[i];
  }
  red[t] = s;
  __syncthreads();
  for (int o = 128; o > 0; o >>= 1) {
    if (t < o) red[t] += red[t + o];
    __syncthreads();
  }
  if (t == 0) bsum[b] = red[0];
}

// ---------------- K3b: exclusive scan of chunk sums (single block) ----------------
__global__ __launch_bounds__(128) void scan_partials_kernel(int* __restrict__ bsum, int nb) {
  __shared__ int buf[128];
  int t = threadIdx.x;
  int v = (t < nb) ? bsum[t] : 0;
  buf[t] = v;
  __syncthreads();
  for (int o = 1; o < 128; o <<= 1) {
    int add = (t >= o) ? buf[t - o] : 0;
    __syncthreads();
    buf[t] += add;
    __syncthreads();
  }
  if (t < nb) bsum[t] = buf[t] - v;  // exclusive
}

// ---------------- K3c: per-chunk exclusive scan + base ----------------
__global__ __launch_bounds__(256) void chunk_scan_kernel(const int* __restrict__ cnt,
                                                         const int* __restrict__ bsum,
                                                         int* __restrict__ off,
                                                         int* __restrict__ cur) {
  __shared__ int buf[256];
  int b = blockIdx.x, t = threadIdx.x;
  int i0 = b * 1024 + t * 4;
  int v[4];
  int s = 0;
  #pragma unroll
  for (int c = 0; c < 4; ++c) {
    int i = i0 + c;
    v[c] = (i < N_NODES) ? cnt[i] : 0;
    s += v[c];
  }
  buf[t] = s;
  __syncthreads();
  for (int o = 1; o < 256; o <<= 1) {
    int add = (t >= o) ? buf[t - o] : 0;
    __syncthreads();
    buf[t] += add;
    __syncthreads();
  }
  int excl = buf[t] - s + bsum[b];
  #pragma unroll
  for (int c = 0; c < 4; ++c) {
    int i = i0 + c;
    if (i < N_NODES) { off[i] = excl; cur[i] = excl; }
    excl += v[c];
  }
  if (b == 0 && t == 0) off[N_NODES] = E_EDGES;
}

// ---------------- K4: scatter dst into per-src segments ----------------
__global__ void scatter_kernel(const int* __restrict__ edges, int* __restrict__ cur,
                               int* __restrict__ sdst, const int* __restrict__ flag) {
  int e = blockIdx.x * blockDim.x + threadIdx.x;
  if (e < E_EDGES) {
    int s, d;
    load_edge(edges, e, *flag, s, d);
    int pos = atomicAdd(&cur[s], 1);
    sdst[pos] = d;
  }
}

// ---------------- K5: one wave per node, lane = output dim ----------------
__global__ __launch_bounds__(256) void aggregate_kernel(
    const float* __restrict__ emb, const float* __restrict__ s1, const float* __restrict__ s2,
    const int* __restrict__ off, const int* __restrict__ sdst, float* __restrict__ out)
{
  const int lane = threadIdx.x & 63;
  const int node = blockIdx.x * 4 + (threadIdx.x >> 6);
  if (node >= N_NODES) return;

  const float si1  = s1[node];
  const float esel = emb[(size_t)node * OUT_DIM + lane];

  // self loop
  float lg = si1 + s2[node];
  float wv = __expf(lg >= 0.f ? lg : SLOPE * lg);
  float acc  = wv * esel;
  float wsum = wv;

  const int beg = off[node], end = off[node + 1];
  for (int j0 = beg; j0 < end; j0 += 64) {
    int dj = 0;
    float s2j = 0.f;
    if (j0 + lane < end) {
      dj  = sdst[j0 + lane];   // coalesced chunk of this node's edge list
      s2j = s2[dj];            // per-lane gather, broadcast later
    }
    int m = min(64, end - j0);
    for (int q = 0; q < m; ++q) {
      int   d  = __shfl(dj,  q, 64);
      float lq = si1 + __shfl(s2j, q, 64);
      float wq = __expf(lq >= 0.f ? lq : SLOPE * lq);
      wsum += wq;
      acc  += wq * emb[(size_t)d * OUT_DIM + lane];  // coalesced 256B line
    }
  }
  out[(size_t)node * OUT_DIM + lane] = acc / wsum;
}

extern "C" void kernel_launch(void* const* d_in, const int* in_sizes, int n_in,
                              void* d_out, int out_size, void* d_ws, size_t ws_size,
                              hipStream_t stream) {
  const float* features = (const float*)d_in[0];
  const float* W        = (const float*)d_in[1];
  const float* b        = (const float*)d_in[2];
  const float* a        = (const float*)d_in[3];
  const int*   edges    = (const int*)d_in[4];
  float* out = (float*)d_out;

  // workspace layout (all 4B types) — ~34 MB total
  float* emb  = (float*)d_ws;                       // N*64
  float* s1   = emb + (size_t)N_NODES * OUT_DIM;    // N
  float* s2   = s1 + N_NODES;                       // N
  int*   cnt  = (int*)(s2 + N_NODES);               // N
  int*   off  = cnt + N_NODES;                      // N+1
  int*   cur  = off + N_NODES + 1;                  // N
  int*   sdst = cur + N_NODES;                      // E
  int*   bsum = sdst + E_EDGES;                     // ~98
  int*   flag = bsum + 128;                         // 1

  const int NB_CHUNK = (N_NODES + 1023) / 1024;     // 98

  hipLaunchKernelGGL(zero_kernel, dim3((N_NODES + 255) / 256), dim3(256), 0, stream,
                     cnt, N_NODES);
  hipLaunchKernelGGL(detect_kernel, dim3(1), dim3(64), 0, stream, edges, flag);
  hipLaunchKernelGGL(embed_kernel, dim3((N_NODES + 63) / 64), dim3(256), 0, stream,
                     features, W, b, a, emb, s1, s2);
  hipLaunchKernelGGL(hist_kernel, dim3((E_EDGES + 255) / 256), dim3(256), 0, stream,
                     edges, cnt, flag);
  hipLaunchKernelGGL(chunk_reduce_kernel, dim3(NB_CHUNK), dim3(256), 0, stream, cnt, bsum);
  hipLaunchKernelGGL(scan_partials_kernel, dim3(1), dim3(128), 0, stream, bsum, NB_CHUNK);
  hipLaunchKernelGGL(chunk_scan_kernel, dim3(NB_CHUNK), dim3(256), 0, stream,
                     cnt, bsum, off, cur);
  hipLaunchKernelGGL(scatter_kernel, dim3((E_EDGES + 255) / 256), dim3(256), 0, stream,
                     edges, cur, sdst, flag);
  hipLaunchKernelGGL(aggregate_kernel, dim3((N_NODES + 3) / 4), dim3(256), 0, stream,
                     emb, s1, s2, off, sdst, out);
}

// Round 2
// 391.545 us; speedup vs baseline: 1.1934x; 1.1934x over previous
//
#include <hip/hip_runtime.h>

#define N_NODES 100000
#define E_EDGES 1600000
#define IN_DIM  256
#define OUT_DIM 64
#define SLOPE   0.1f

#define BM 128
#define BK 64
#define WPAD 68   // W-tile row stride in floats (272B, 16B-aligned, breaks bank alias)

// ---------------- K0: zero histogram + detect int32/int64 edge layout ----------------
__global__ void zero_detect_kernel(int* __restrict__ cnt, const int* __restrict__ edges,
                                   int* __restrict__ flag) {
  int i = blockIdx.x * blockDim.x + threadIdx.x;
  if (i < N_NODES) cnt[i] = 0;
  if (i == 0) {
    int all0 = 1;
    for (int j = 0; j < 64; ++j)
      if (edges[2 * j + 1] != 0) all0 = 0;
    *flag = all0;  // 1 => int64 layout (high dwords zero), 0 => int32
  }
}

// ---------------- K1: emb = X@W^T + b  (register-blocked fp32 GEMM) ----------------
// 256 thr = 4 waves. tx=t>>4 (col group, 4 cols each), ty=t&15 (rows ty+16r, r=0..7).
__global__ __launch_bounds__(256) void embed_kernel(
    const float* __restrict__ features, const float* __restrict__ W,
    const float* __restrict__ bias, float* __restrict__ emb)
{
  __shared__ __align__(16) float ft[BM * BK];        // A tile, XOR-swizzled, 32 KB
  __shared__ __align__(16) float wt[OUT_DIM * WPAD]; // B tile, col-major padded, 17 KB

  const int t  = threadIdx.x;
  const int tx = t >> 4;
  const int ty = t & 15;
  const int row0 = blockIdx.x * BM;

  const float4 bv = *(const float4*)&bias[tx * 4];
  float acc[8][4];
  #pragma unroll
  for (int r = 0; r < 8; ++r) {
    acc[r][0] = bv.x; acc[r][1] = bv.y; acc[r][2] = bv.z; acc[r][3] = bv.w;
  }

  const int lrow = t >> 4;   // staging: row group
  const int lc   = t & 15;   // staging: float4 column
  const int wcol = t >> 2;   // W staging: output col
  const int wq   = t & 3;

  for (int ks = 0; ks < IN_DIM / BK; ++ks) {
    // ---- stage A tile (128 x 64 fp32), swizzled float4 index ----
    #pragma unroll
    for (int i = 0; i < 8; ++i) {
      const int row = lrow + 16 * i;
      float4 fv = make_float4(0.f, 0.f, 0.f, 0.f);
      if (row0 + row < N_NODES)
        fv = *(const float4*)&features[(size_t)(row0 + row) * IN_DIM + ks * BK + lc * 4];
      *(float4*)&ft[row * BK + ((lc ^ (row & 7)) * 4)] = fv;
    }
    // ---- stage W tile (64 cols x 64 k), col-major with pad ----
    #pragma unroll
    for (int i = 0; i < 4; ++i) {
      const int j = wq + 4 * i;  // float4 index along k
      const float4 wv = *(const float4*)&W[(size_t)wcol * IN_DIM + ks * BK + j * 4];
      *(float4*)&wt[wcol * WPAD + j * 4] = wv;
    }
    __syncthreads();

    #pragma unroll 4
    for (int k4 = 0; k4 < BK / 4; ++k4) {
      float4 bf[4];
      #pragma unroll
      for (int c = 0; c < 4; ++c)
        bf[c] = *(const float4*)&wt[(tx * 4 + c) * WPAD + k4 * 4];
      #pragma unroll
      for (int r = 0; r < 8; ++r) {
        const int row = ty + 16 * r;  // row&7 == ty&7
        const float4 af = *(const float4*)&ft[row * BK + ((k4 ^ (ty & 7)) * 4)];
        #pragma unroll
        for (int c = 0; c < 4; ++c)
          acc[r][c] += af.x * bf[c].x + af.y * bf[c].y + af.z * bf[c].z + af.w * bf[c].w;
      }
    }
    __syncthreads();
  }

  #pragma unroll
  for (int r = 0; r < 8; ++r) {
    const int row = row0 + ty + 16 * r;
    if (row < N_NODES) {
      float4 ov = make_float4(acc[r][0], acc[r][1], acc[r][2], acc[r][3]);
      *(float4*)&emb[(size_t)row * OUT_DIM + tx * 4] = ov;
    }
  }
}

// ---------------- K1b: s1 = emb@a1, s2 = emb@a2 (wave per node) ----------------
__global__ __launch_bounds__(256) void sdot_kernel(
    const float* __restrict__ emb, const float* __restrict__ a,
    float* __restrict__ s1, float* __restrict__ s2)
{
  const int lane = threadIdx.x & 63;
  const int node = blockIdx.x * 4 + (threadIdx.x >> 6);
  if (node >= N_NODES) return;
  const float e = emb[(size_t)node * OUT_DIM + lane];
  float p1 = e * a[lane];
  float p2 = e * a[OUT_DIM + lane];
  #pragma unroll
  for (int o = 32; o > 0; o >>= 1) {
    p1 += __shfl_xor(p1, o, 64);
    p2 += __shfl_xor(p2, o, 64);
  }
  if (lane == 0) { s1[node] = p1; s2[node] = p2; }
}

// ---------------- K2: histogram of src ----------------
__global__ void hist_kernel(const int* __restrict__ edges, int* __restrict__ cnt,
                            const int* __restrict__ flag) {
  const int e = blockIdx.x * blockDim.x + threadIdx.x;
  if (e >= E_EDGES) return;
  int s;
  if (*flag) { int4 v = ((const int4*)edges)[e]; s = v.x; }
  else       { int2 v = ((const int2*)edges)[e]; s = v.x; }
  atomicAdd(&cnt[s], 1);
}

// ---------------- K3a: per-1024-chunk sums ----------------
__global__ __launch_bounds__(256) void chunk_reduce_kernel(const int* __restrict__ cnt,
                                                           int* __restrict__ bsum) {
  __shared__ int red[256];
  int b = blockIdx.x, t = threadIdx.x;
  int base = b * 1024;
  int s = 0;
  for (int j = t; j < 1024; j += 256) {
    int i = base + j;
    if (i < N_NODES) s += cnt[i];
  }
  red[t] = s;
  __syncthreads();
  for (int o = 128; o > 0; o >>= 1) {
    if (t < o) red[t] += red[t + o];
    __syncthreads();
  }
  if (t == 0) bsum[b] = red[0];
}

// ---------------- K3b: exclusive scan of chunk sums ----------------
__global__ __launch_bounds__(128) void scan_partials_kernel(int* __restrict__ bsum, int nb) {
  __shared__ int buf[128];
  int t = threadIdx.x;
  int v = (t < nb) ? bsum[t] : 0;
  buf[t] = v;
  __syncthreads();
  for (int o = 1; o < 128; o <<= 1) {
    int add = (t >= o) ? buf[t - o] : 0;
    __syncthreads();
    buf[t] += add;
    __syncthreads();
  }
  if (t < nb) bsum[t] = buf[t] - v;  // exclusive
}

// ---------------- K3c: per-chunk exclusive scan + base ----------------
__global__ __launch_bounds__(256) void chunk_scan_kernel(const int* __restrict__ cnt,
                                                         const int* __restrict__ bsum,
                                                         int* __restrict__ off,
                                                         int* __restrict__ cur) {
  __shared__ int buf[256];
  int b = blockIdx.x, t = threadIdx.x;
  int i0 = b * 1024 + t * 4;
  int v[4];
  int s = 0;
  #pragma unroll
  for (int c = 0; c < 4; ++c) {
    int i = i0 + c;
    v[c] = (i < N_NODES) ? cnt[i] : 0;
    s += v[c];
  }
  buf[t] = s;
  __syncthreads();
  for (int o = 1; o < 256; o <<= 1) {
    int add = (t >= o) ? buf[t - o] : 0;
    __syncthreads();
    buf[t] += add;
    __syncthreads();
  }
  int excl = buf[t] - s + bsum[b];
  #pragma unroll
  for (int c = 0; c < 4; ++c) {
    int i = i0 + c;
    if (i < N_NODES) { off[i] = excl; cur[i] = excl; }
    excl += v[c];
  }
  if (b == 0 && t == 0) off[N_NODES] = E_EDGES;
}

// ---------------- K4: scatter dst (+ optional precomputed weight) ----------------
template<bool UW>
__global__ void scatter_kernel(const int* __restrict__ edges, int* __restrict__ cur,
                               int* __restrict__ sdst, float* __restrict__ sw,
                               const float* __restrict__ s1, const float* __restrict__ s2,
                               const int* __restrict__ flag) {
  const int e = blockIdx.x * blockDim.x + threadIdx.x;
  if (e >= E_EDGES) return;
  int s, d;
  if (*flag) { int4 v = ((const int4*)edges)[e]; s = v.x; d = v.z; }
  else       { int2 v = ((const int2*)edges)[e]; s = v.x; d = v.y; }
  int pos = atomicAdd(&cur[s], 1);
  sdst[pos] = d;
  if (UW) {
    float lg = s1[s] + s2[d];
    sw[pos] = __expf(lg >= 0.f ? lg : SLOPE * lg);
  }
}

// ---------------- K5: one wave per node, lane = output dim ----------------
template<bool UW>
__global__ __launch_bounds__(256) void aggregate_kernel(
    const float* __restrict__ emb, const float* __restrict__ s1, const float* __restrict__ s2,
    const int* __restrict__ off, const int* __restrict__ sdst, const float* __restrict__ sw,
    float* __restrict__ out)
{
  const int lane = threadIdx.x & 63;
  const int node = blockIdx.x * 4 + (threadIdx.x >> 6);
  if (node >= N_NODES) return;

  const float si1  = s1[node];
  const float esel = emb[(size_t)node * OUT_DIM + lane];

  // self loop
  float lg = si1 + s2[node];
  float wv = __expf(lg >= 0.f ? lg : SLOPE * lg);
  float acc  = wv * esel;
  float wsum = wv;

  const int beg = off[node], end = off[node + 1];
  for (int j0 = beg; j0 < end; j0 += 64) {
    int dj = 0;
    float wjl = 0.f;
    if (j0 + lane < end) {
      dj = sdst[j0 + lane];
      wjl = UW ? sw[j0 + lane] : s2[dj];
    }
    const int m = min(64, end - j0);
    for (int q = 0; q < m; ++q) {
      const int   d = __shfl(dj, q, 64);
      float wq;
      if (UW) {
        wq = __shfl(wjl, q, 64);
      } else {
        float lq = si1 + __shfl(wjl, q, 64);
        wq = __expf(lq >= 0.f ? lq : SLOPE * lq);
      }
      wsum += wq;
      acc  += wq * emb[(size_t)d * OUT_DIM + lane];
    }
  }
  out[(size_t)node * OUT_DIM + lane] = acc / wsum;
}

extern "C" void kernel_launch(void* const* d_in, const int* in_sizes, int n_in,
                              void* d_out, int out_size, void* d_ws, size_t ws_size,
                              hipStream_t stream) {
  const float* features = (const float*)d_in[0];
  const float* W        = (const float*)d_in[1];
  const float* b        = (const float*)d_in[2];
  const float* a        = (const float*)d_in[3];
  const int*   edges    = (const int*)d_in[4];
  float* out = (float*)d_out;

  // workspace layout (4B units)
  float* emb  = (float*)d_ws;                       // N*64
  float* s1   = emb + (size_t)N_NODES * OUT_DIM;    // N
  float* s2   = s1 + N_NODES;                       // N
  int*   cnt  = (int*)(s2 + N_NODES);               // N
  int*   off  = cnt + N_NODES;                      // N+1
  int*   cur  = off + N_NODES + 1;                  // N
  int*   bsum = cur + N_NODES;                      // 128
  int*   flag = bsum + 128;                         // 1 (+pad to 8)
  int*   sdst = flag + 7;                           // E
  float* sw   = (float*)(sdst + E_EDGES);           // E (optional)

  const size_t base_elems = (size_t)(sdst + E_EDGES - (int*)d_ws);
  const bool use_w = ws_size >= (base_elems + E_EDGES) * 4;

  const int NB_CHUNK = (N_NODES + 1023) / 1024;     // 98

  hipLaunchKernelGGL(zero_detect_kernel, dim3((N_NODES + 255) / 256), dim3(256), 0, stream,
                     cnt, edges, flag);
  hipLaunchKernelGGL(embed_kernel, dim3((N_NODES + BM - 1) / BM), dim3(256), 0, stream,
                     features, W, b, emb);
  hipLaunchKernelGGL(sdot_kernel, dim3((N_NODES + 3) / 4), dim3(256), 0, stream,
                     emb, a, s1, s2);
  hipLaunchKernelGGL(hist_kernel, dim3((E_EDGES + 255) / 256), dim3(256), 0, stream,
                     edges, cnt, flag);
  hipLaunchKernelGGL(chunk_reduce_kernel, dim3(NB_CHUNK), dim3(256), 0, stream, cnt, bsum);
  hipLaunchKernelGGL(scan_partials_kernel, dim3(1), dim3(128), 0, stream, bsum, NB_CHUNK);
  hipLaunchKernelGGL(chunk_scan_kernel, dim3(NB_CHUNK), dim3(256), 0, stream,
                     cnt, bsum, off, cur);
  if (use_w) {
    hipLaunchKernelGGL((scatter_kernel<true>), dim3((E_EDGES + 255) / 256), dim3(256), 0, stream,
                       edges, cur, sdst, sw, s1, s2, flag);
    hipLaunchKernelGGL((aggregate_kernel<true>), dim3((N_NODES + 3) / 4), dim3(256), 0, stream,
                       emb, s1, s2, off, sdst, sw, out);
  } else {
    hipLaunchKernelGGL((scatter_kernel<false>), dim3((E_EDGES + 255) / 256), dim3(256), 0, stream,
                       edges, cur, sdst, sw, s1, s2, flag);
    hipLaunchKernelGGL((aggregate_kernel<false>), dim3((N_NODES + 3) / 4), dim3(256), 0, stream,
                       emb, s1, s2, off, sdst, sw, out);
  }
}

// Round 3
// 215.249 us; speedup vs baseline: 2.1708x; 1.8190x over previous
//
#include <hip/hip_runtime.h>

#define N_NODES 100000
#define E_EDGES 1600000
#define IN_DIM  256
#define OUT_DIM 64
#define SLOPE   0.1f

#define BM 128
#define BK 64
#define WPAD 68   // W-tile row stride in floats (272B, 16B-aligned, breaks bank alias)

#define BKT_SHIFT  7
#define BKT_NODES  128
#define NBKT       ((N_NODES + BKT_NODES - 1) / BKT_NODES)   // 782
#define BUCKET_CAP 3072      // max edges per bucket (mean 2046, sigma ~45)
#define SC_BLOCK   1024
#define SC_EPT     16
#define SC_EDGES   (SC_BLOCK * SC_EPT)                        // 16384
#define SC_GRID    ((E_EDGES + SC_EDGES - 1) / SC_EDGES)      // 98

// ---------------- K0: zero bucket counters + detect int32/int64 edge layout ----------------
__global__ void zero_detect_kernel(int* __restrict__ bcnt, const int* __restrict__ edges,
                                   int* __restrict__ flag) {
  int i = blockIdx.x * blockDim.x + threadIdx.x;
  if (i < NBKT) bcnt[i] = 0;
  if (i == 0) {
    int all0 = 1;
    for (int j = 0; j < 64; ++j)
      if (edges[2 * j + 1] != 0) all0 = 0;
    *flag = all0;  // 1 => int64 layout (high dwords zero), 0 => int32
  }
}

// ---------------- K1: emb = X@W^T + b (register-blocked fp32 GEMM) + fused bucket hist ----
// 256 thr = 4 waves. tx=t>>4 (col group, 4 cols each), ty=t&15 (rows ty+16r, r=0..7).
// Grid = ceil(N/128) = 782 = NBKT; each block also histograms 2048 edges.
__global__ __launch_bounds__(256) void embed_kernel(
    const float* __restrict__ features, const float* __restrict__ W,
    const float* __restrict__ bias, float* __restrict__ emb,
    const int* __restrict__ edges, const int* __restrict__ flag, int* __restrict__ bcnt)
{
  __shared__ __align__(16) float ft[BM * BK];        // A tile, XOR-swizzled, 32 KB
  __shared__ __align__(16) float wt[OUT_DIM * WPAD]; // B tile, col-major padded, 17 KB

  const int t  = threadIdx.x;
  const int tx = t >> 4;
  const int ty = t & 15;
  const int row0 = blockIdx.x * BM;

  const float4 bv = *(const float4*)&bias[tx * 4];
  float acc[8][4];
  #pragma unroll
  for (int r = 0; r < 8; ++r) {
    acc[r][0] = bv.x; acc[r][1] = bv.y; acc[r][2] = bv.z; acc[r][3] = bv.w;
  }

  const int lrow = t >> 4;   // staging: row group
  const int lc   = t & 15;   // staging: float4 column
  const int wcol = t >> 2;   // W staging: output col
  const int wq   = t & 3;

  for (int ks = 0; ks < IN_DIM / BK; ++ks) {
    #pragma unroll
    for (int i = 0; i < 8; ++i) {
      const int row = lrow + 16 * i;
      float4 fv = make_float4(0.f, 0.f, 0.f, 0.f);
      if (row0 + row < N_NODES)
        fv = *(const float4*)&features[(size_t)(row0 + row) * IN_DIM + ks * BK + lc * 4];
      *(float4*)&ft[row * BK + ((lc ^ (row & 7)) * 4)] = fv;
    }
    #pragma unroll
    for (int i = 0; i < 4; ++i) {
      const int j = wq + 4 * i;
      const float4 wv = *(const float4*)&W[(size_t)wcol * IN_DIM + ks * BK + j * 4];
      *(float4*)&wt[wcol * WPAD + j * 4] = wv;
    }
    __syncthreads();

    #pragma unroll 4
    for (int k4 = 0; k4 < BK / 4; ++k4) {
      float4 bf[4];
      #pragma unroll
      for (int c = 0; c < 4; ++c)
        bf[c] = *(const float4*)&wt[(tx * 4 + c) * WPAD + k4 * 4];
      #pragma unroll
      for (int r = 0; r < 8; ++r) {
        const int row = ty + 16 * r;
        const float4 af = *(const float4*)&ft[row * BK + ((k4 ^ (ty & 7)) * 4)];
        #pragma unroll
        for (int c = 0; c < 4; ++c)
          acc[r][c] += af.x * bf[c].x + af.y * bf[c].y + af.z * bf[c].z + af.w * bf[c].w;
      }
    }
    __syncthreads();
  }

  #pragma unroll
  for (int r = 0; r < 8; ++r) {
    const int row = row0 + ty + 16 * r;
    if (row < N_NODES) {
      float4 ov = make_float4(acc[r][0], acc[r][1], acc[r][2], acc[r][3]);
      *(float4*)&emb[(size_t)row * OUT_DIM + tx * 4] = ov;
    }
  }

  // ---- fused bucket histogram over this block's 2048-edge chunk ----
  int* lh = (int*)ft;   // reuse A-tile LDS (all waves past final k-loop barrier)
  for (int j = t; j < NBKT; j += 256) lh[j] = 0;
  __syncthreads();
  const int is64 = *flag;
  const int e0 = blockIdx.x * 2048;
  #pragma unroll
  for (int i = 0; i < 8; ++i) {
    const int e = e0 + t + i * 256;
    if (e < E_EDGES) {
      const int s = is64 ? ((const int4*)edges)[e].x : ((const int2*)edges)[e].x;
      atomicAdd(&lh[s >> BKT_SHIFT], 1);
    }
  }
  __syncthreads();
  for (int j = t; j < NBKT; j += 256)
    if (lh[j]) atomicAdd(&bcnt[j], lh[j]);
}

// ---------------- K1b: s1 = emb@a1, s2 = emb@a2 (wave per node) ----------------
__global__ __launch_bounds__(256) void sdot_kernel(
    const float* __restrict__ emb, const float* __restrict__ a,
    float* __restrict__ s1, float* __restrict__ s2)
{
  const int lane = threadIdx.x & 63;
  const int node = blockIdx.x * 4 + (threadIdx.x >> 6);
  if (node >= N_NODES) return;
  const float e = emb[(size_t)node * OUT_DIM + lane];
  float p1 = e * a[lane];
  float p2 = e * a[OUT_DIM + lane];
  #pragma unroll
  for (int o = 32; o > 0; o >>= 1) {
    p1 += __shfl_xor(p1, o, 64);
    p2 += __shfl_xor(p2, o, 64);
  }
  if (lane == 0) { s1[node] = p1; s2[node] = p2; }
}

// ---------------- K2: exclusive scan of bucket counts (single block) ----------------
__global__ __launch_bounds__(1024) void bucket_scan_kernel(const int* __restrict__ bcnt,
                                                           int* __restrict__ bbase,
                                                           int* __restrict__ bcur) {
  __shared__ int buf[1024];
  const int t = threadIdx.x;
  const int v = (t < NBKT) ? bcnt[t] : 0;
  buf[t] = v;
  __syncthreads();
  for (int o = 1; o < 1024; o <<= 1) {
    int add = (t >= o) ? buf[t - o] : 0;
    __syncthreads();
    buf[t] += add;
    __syncthreads();
  }
  if (t < NBKT) {
    const int ex = buf[t] - v;
    bbase[t] = ex;
    bcur[t]  = ex;
  }
  if (t == 0) bbase[NBKT] = E_EDGES;
}

// ---------------- K3: bucket scatter (single pass, edges cached in VGPRs) ----------------
__global__ __launch_bounds__(SC_BLOCK) void bucket_scatter_kernel(
    const int* __restrict__ edges, int* __restrict__ bcur,
    int2* __restrict__ pairs, const int* __restrict__ flag)
{
  __shared__ int lh[NBKT];     // per-block bucket counts, then reused as per-bucket cursor
  __shared__ int lbase[NBKT];  // reserved global base per bucket
  const int t = threadIdx.x;
  for (int j = t; j < NBKT; j += SC_BLOCK) lh[j] = 0;
  __syncthreads();

  const int is64 = *flag;
  const int e0 = blockIdx.x * SC_EDGES;
  int ss[SC_EPT], dd[SC_EPT];
  #pragma unroll
  for (int i = 0; i < SC_EPT; ++i) {
    const int e = e0 + t + i * SC_BLOCK;
    int s = -1, d = 0;
    if (e < E_EDGES) {
      if (is64) { int4 v = ((const int4*)edges)[e]; s = v.x; d = v.z; }
      else      { int2 v = ((const int2*)edges)[e]; s = v.x; d = v.y; }
      atomicAdd(&lh[s >> BKT_SHIFT], 1);
    }
    ss[i] = s; dd[i] = d;
  }
  __syncthreads();
  for (int j = t; j < NBKT; j += SC_BLOCK) {
    const int c = lh[j];
    lbase[j] = c ? atomicAdd(&bcur[j], c) : 0;
  }
  __syncthreads();
  for (int j = t; j < NBKT; j += SC_BLOCK) lh[j] = 0;   // reuse as cursor
  __syncthreads();
  #pragma unroll
  for (int i = 0; i < SC_EPT; ++i) {
    const int s = ss[i];
    if (s >= 0) {
      const int b = s >> BKT_SHIFT;
      const int pos = lbase[b] + atomicAdd(&lh[b], 1);
      pairs[pos] = make_int2(s, dd[i]);
    }
  }
}

// ---------------- K4: per-bucket counting sort + weight precompute (in place) --------
// One block per bucket. Produces off[] and rewrites pairs[] as (dst, w_bits) sorted by src.
__global__ __launch_bounds__(256) void bucket_sort_kernel(
    const float* __restrict__ s1, const float* __restrict__ s2,
    const int* __restrict__ bbase, int2* __restrict__ pairs, int* __restrict__ off)
{
  __shared__ int2  lp[BUCKET_CAP];     // 24 KB
  __shared__ int   hist[BKT_NODES];
  __shared__ int   loff[BKT_NODES];
  __shared__ float ls1[BKT_NODES];
  const int b = blockIdx.x, t = threadIdx.x;
  const int nbase = b << BKT_SHIFT;
  const int nn = min(BKT_NODES, N_NODES - nbase);
  const int beg = bbase[b], end = bbase[b + 1];
  const int cnt = min(end - beg, BUCKET_CAP);

  if (t < BKT_NODES) {
    hist[t] = 0;
    if (t < nn) ls1[t] = s1[nbase + t];
  }
  __syncthreads();
  for (int j = t; j < cnt; j += 256) {
    const int2 p = pairs[beg + j];
    lp[j] = p;
    atomicAdd(&hist[p.x - nbase], 1);
  }
  __syncthreads();
  // inclusive scan of hist -> loff
  if (t < BKT_NODES) loff[t] = hist[t];
  __syncthreads();
  for (int o = 1; o < BKT_NODES; o <<= 1) {
    int add = 0;
    if (t < BKT_NODES && t >= o) add = loff[t - o];
    __syncthreads();
    if (t < BKT_NODES) loff[t] += add;
    __syncthreads();
  }
  int excl = 0;
  if (t < BKT_NODES) {
    excl = loff[t] - hist[t];
    if (t < nn) off[nbase + t] = beg + excl;
  }
  if (b == NBKT - 1 && t == 0) off[N_NODES] = E_EDGES;
  __syncthreads();
  if (t < BKT_NODES) { loff[t] = excl; hist[t] = 0; }  // hist reused as cursor
  __syncthreads();
  for (int j = t; j < cnt; j += 256) {
    const int2 p = lp[j];
    const int li = p.x - nbase;
    const int pos = beg + loff[li] + atomicAdd(&hist[li], 1);
    const float lg = ls1[li] + s2[p.y];
    const float w = __expf(lg >= 0.f ? lg : SLOPE * lg);
    pairs[pos] = make_int2(p.y, __float_as_int(w));
  }
}

// ---------------- K5: one wave per node, lane = output dim ----------------
__global__ __launch_bounds__(256) void aggregate_kernel(
    const float* __restrict__ emb, const float* __restrict__ s1, const float* __restrict__ s2,
    const int* __restrict__ off, const int2* __restrict__ pairs, float* __restrict__ out)
{
  const int lane = threadIdx.x & 63;
  const int node = blockIdx.x * 4 + (threadIdx.x >> 6);
  if (node >= N_NODES) return;

  const float esel = emb[(size_t)node * OUT_DIM + lane];
  const float lg = s1[node] + s2[node];
  const float wself = __expf(lg >= 0.f ? lg : SLOPE * lg);
  float acc0 = wself * esel, acc1 = 0.f, acc2 = 0.f, acc3 = 0.f;
  float wsum = wself;

  const int beg = off[node], end = off[node + 1];
  for (int j0 = beg; j0 < end; j0 += 64) {
    int dj = 0; float wj = 0.f;
    if (j0 + lane < end) {
      const int2 p = pairs[j0 + lane];
      dj = p.x;
      wj = __int_as_float(p.y);
    }
    const int m = min(64, end - j0);
    int q = 0;
    for (; q + 4 <= m; q += 4) {
      const int   d0 = __shfl(dj, q, 64),     d1 = __shfl(dj, q + 1, 64);
      const int   d2 = __shfl(dj, q + 2, 64), d3 = __shfl(dj, q + 3, 64);
      const float w0 = __shfl(wj, q, 64),     w1 = __shfl(wj, q + 1, 64);
      const float w2 = __shfl(wj, q + 2, 64), w3 = __shfl(wj, q + 3, 64);
      const float e0 = emb[(size_t)d0 * OUT_DIM + lane];
      const float e1 = emb[(size_t)d1 * OUT_DIM + lane];
      const float e2 = emb[(size_t)d2 * OUT_DIM + lane];
      const float e3 = emb[(size_t)d3 * OUT_DIM + lane];
      acc0 += w0 * e0; acc1 += w1 * e1; acc2 += w2 * e2; acc3 += w3 * e3;
      wsum += w0 + w1 + w2 + w3;
    }
    for (; q < m; ++q) {
      const int   d = __shfl(dj, q, 64);
      const float w = __shfl(wj, q, 64);
      acc0 += w * emb[(size_t)d * OUT_DIM + lane];
      wsum += w;
    }
  }
  out[(size_t)node * OUT_DIM + lane] = (acc0 + acc1 + acc2 + acc3) / wsum;
}

extern "C" void kernel_launch(void* const* d_in, const int* in_sizes, int n_in,
                              void* d_out, int out_size, void* d_ws, size_t ws_size,
                              hipStream_t stream) {
  const float* features = (const float*)d_in[0];
  const float* W        = (const float*)d_in[1];
  const float* b        = (const float*)d_in[2];
  const float* a        = (const float*)d_in[3];
  const int*   edges    = (const int*)d_in[4];
  float* out = (float*)d_out;

  // workspace layout (4B units), ~39.6 MB total
  float* emb   = (float*)d_ws;                       // N*64
  float* s1    = emb + (size_t)N_NODES * OUT_DIM;    // N
  float* s2    = s1 + N_NODES;                       // N
  int*   off   = (int*)(s2 + N_NODES);               // N+1
  int*   bcnt  = off + N_NODES + 1;                  // NBKT
  int*   bbase = bcnt + NBKT;                        // NBKT+1
  int*   bcur  = bbase + NBKT + 1;                   // NBKT
  int*   flag  = bcur + NBKT;                        // 1 (+pad)
  int2*  pairs = (int2*)(flag + 8);                  // E (8B each)

  hipLaunchKernelGGL(zero_detect_kernel, dim3((NBKT + 255) / 256), dim3(256), 0, stream,
                     bcnt, edges, flag);
  hipLaunchKernelGGL(embed_kernel, dim3((N_NODES + BM - 1) / BM), dim3(256), 0, stream,
                     features, W, b, emb, edges, flag, bcnt);
  hipLaunchKernelGGL(sdot_kernel, dim3((N_NODES + 3) / 4), dim3(256), 0, stream,
                     emb, a, s1, s2);
  hipLaunchKernelGGL(bucket_scan_kernel, dim3(1), dim3(1024), 0, stream,
                     bcnt, bbase, bcur);
  hipLaunchKernelGGL(bucket_scatter_kernel, dim3(SC_GRID), dim3(SC_BLOCK), 0, stream,
                     edges, bcur, pairs, flag);
  hipLaunchKernelGGL(bucket_sort_kernel, dim3(NBKT), dim3(256), 0, stream,
                     s1, s2, bbase, pairs, off);
  hipLaunchKernelGGL(aggregate_kernel, dim3((N_NODES + 3) / 4), dim3(256), 0, stream,
                     emb, s1, s2, off, pairs, out);
}

// Round 4
// 178.842 us; speedup vs baseline: 2.6127x; 1.2036x over previous
//
#include <hip/hip_runtime.h>

#define N_NODES 100000
#define E_EDGES 1600000
#define IN_DIM  256
#define OUT_DIM 64
#define SLOPE   0.1f

#define BKT_SHIFT  7
#define BKT_NODES  128
#define NBKT       ((N_NODES + BKT_NODES - 1) / BKT_NODES)   // 782
#define BUCKET_CAP 3072
#define SC_BLOCK   1024
#define SC_EPT     16
#define SC_EDGES   (SC_BLOCK * SC_EPT)                        // 16384
#define SC_GRID    ((E_EDGES + SC_EDGES - 1) / SC_EDGES)      // 98

typedef __attribute__((ext_vector_type(8))) short bhalf8;
typedef __attribute__((ext_vector_type(4))) float f32x4;

__device__ __forceinline__ unsigned short f2bf(float x) {
  unsigned u = __float_as_uint(x);
  u = (u + 0x7fffu + ((u >> 16) & 1u)) >> 16;   // RNE
  return (unsigned short)u;
}

// ---------------- K0: zero bucket counters + detect int32/int64 edge layout ----------------
__global__ void zero_detect_kernel(int* __restrict__ bcnt, const int* __restrict__ edges,
                                   int* __restrict__ flag) {
  int i = blockIdx.x * blockDim.x + threadIdx.x;
  if (i < NBKT) bcnt[i] = 0;
  if (i == 0) {
    int all0 = 1;
    for (int j = 0; j < 64; ++j)
      if (edges[2 * j + 1] != 0) all0 = 0;
    *flag = all0;  // 1 => int64 layout (high dwords zero), 0 => int32
  }
}

// ---------------- K1: emb = bf16( X@W^T ) + b via MFMA, fused s1/s2 + bucket hist -------
// 782 blocks x 256 thr (4 waves). Block stages A[128][256]bf16 (64KB) + W[64][256]bf16
// (32KB), XOR-swizzled; wave w computes rows w*32..w*32+31 x all 64 cols.
__global__ __launch_bounds__(256) void embed_kernel(
    const float* __restrict__ features, const float* __restrict__ W,
    const float* __restrict__ bias, const float* __restrict__ a,
    float* __restrict__ emb, float* __restrict__ s1, float* __restrict__ s2,
    const int* __restrict__ edges, const int* __restrict__ flag, int* __restrict__ bcnt)
{
  __shared__ short Alds[128 * 256];   // 64 KB, row stride 512 B, byte^((row&7)<<4)
  __shared__ short Wlds[64 * 256];    // 32 KB, col stride 512 B, byte^((col&7)<<4)

  const int t = threadIdx.x;
  const int w = t >> 6;
  const int l = t & 63;
  const int lg = l >> 4;      // 0..3  (k-chunk group)
  const int lr = l & 15;      // 0..15 (row/col within tile)
  const int row0 = blockIdx.x * 128;

  // ---- stage W: thread t -> col=t>>2, k-quarter=(t&3)*64 floats ----
  {
    const int col = t >> 2;
    const int kq  = (t & 3) * 64;
    const float* src = &W[(size_t)col * IN_DIM + kq];
    char* dstbase = (char*)Wlds + col * 512;
    #pragma unroll
    for (int j = 0; j < 8; ++j) {
      const float4 f0 = *(const float4*)&src[j * 8];
      const float4 f1 = *(const float4*)&src[j * 8 + 4];
      bhalf8 v;
      v[0] = f2bf(f0.x); v[1] = f2bf(f0.y); v[2] = f2bf(f0.z); v[3] = f2bf(f0.w);
      v[4] = f2bf(f1.x); v[5] = f2bf(f1.y); v[6] = f2bf(f1.z); v[7] = f2bf(f1.w);
      *(bhalf8*)(dstbase + (((kq * 2 + j * 16)) ^ ((col & 7) << 4))) = v;
    }
  }
  // ---- stage A: thread t -> row=t>>1, k-half=(t&1)*128 floats ----
  {
    const int row = t >> 1;
    const int kh  = (t & 1) * 128;
    const int rowc = min(row0 + row, N_NODES - 1);   // clamp (results discarded OOB)
    const float* src = &features[(size_t)rowc * IN_DIM + kh];
    char* dstbase = (char*)Alds + row * 512;
    #pragma unroll
    for (int j = 0; j < 16; ++j) {
      const float4 f0 = *(const float4*)&src[j * 8];
      const float4 f1 = *(const float4*)&src[j * 8 + 4];
      bhalf8 v;
      v[0] = f2bf(f0.x); v[1] = f2bf(f0.y); v[2] = f2bf(f0.z); v[3] = f2bf(f0.w);
      v[4] = f2bf(f1.x); v[5] = f2bf(f1.y); v[6] = f2bf(f1.z); v[7] = f2bf(f1.w);
      *(bhalf8*)(dstbase + (((kh * 2 + j * 16)) ^ ((row & 7) << 4))) = v;
    }
  }
  __syncthreads();

  // ---- MFMA: wave tile 32 rows x 64 cols = 2x4 tiles of 16x16, K=256 in 8 steps ----
  float bc[4];
  #pragma unroll
  for (int ct = 0; ct < 4; ++ct) bc[ct] = bias[ct * 16 + lr];

  f32x4 acc[2][4];
  #pragma unroll
  for (int rt = 0; rt < 2; ++rt)
    #pragma unroll
    for (int ct = 0; ct < 4; ++ct) {
      acc[rt][ct][0] = bc[ct]; acc[rt][ct][1] = bc[ct];
      acc[rt][ct][2] = bc[ct]; acc[rt][ct][3] = bc[ct];
    }

  const int ksw = (lr & 7) << 4;   // lane's swizzle term (row&7 == col&7 == lr&7)
  #pragma unroll
  for (int ks = 0; ks < 8; ++ks) {
    const int koff = lg * 16 + ks * 64;
    bhalf8 af[2], bf[4];
    #pragma unroll
    for (int rt = 0; rt < 2; ++rt) {
      const int row_l = w * 32 + rt * 16 + lr;
      af[rt] = *(const bhalf8*)((const char*)Alds + row_l * 512 + (koff ^ ksw));
    }
    #pragma unroll
    for (int ct = 0; ct < 4; ++ct) {
      const int col_l = ct * 16 + lr;
      bf[ct] = *(const bhalf8*)((const char*)Wlds + col_l * 512 + (koff ^ ksw));
    }
    #pragma unroll
    for (int rt = 0; rt < 2; ++rt)
      #pragma unroll
      for (int ct = 0; ct < 4; ++ct)
        acc[rt][ct] = __builtin_amdgcn_mfma_f32_16x16x32_bf16(af[rt], bf[ct], acc[rt][ct], 0, 0, 0);
  }

  // ---- epilogue: emb writes + fused s1/s2 (row dots with a1,a2) ----
  float a1c[4], a2c[4];
  #pragma unroll
  for (int ct = 0; ct < 4; ++ct) {
    a1c[ct] = a[ct * 16 + lr];
    a2c[ct] = a[OUT_DIM + ct * 16 + lr];
  }
  #pragma unroll
  for (int rt = 0; rt < 2; ++rt) {
    #pragma unroll
    for (int i = 0; i < 4; ++i) {
      const int row = row0 + w * 32 + rt * 16 + lg * 4 + i;
      float p1 = 0.f, p2 = 0.f;
      #pragma unroll
      for (int ct = 0; ct < 4; ++ct) {
        const float e = acc[rt][ct][i];
        p1 += e * a1c[ct];
        p2 += e * a2c[ct];
        if (row < N_NODES) emb[(size_t)row * OUT_DIM + ct * 16 + lr] = e;
      }
      #pragma unroll
      for (int o = 1; o < 16; o <<= 1) {
        p1 += __shfl_xor(p1, o, 64);
        p2 += __shfl_xor(p2, o, 64);
      }
      if (lr == 0 && row < N_NODES) { s1[row] = p1; s2[row] = p2; }
    }
  }

  // ---- fused bucket histogram over this block's 2048-edge chunk ----
  __syncthreads();
  int* lh = (int*)Alds;
  for (int j = t; j < NBKT; j += 256) lh[j] = 0;
  __syncthreads();
  const int is64 = *flag;
  const int e0 = blockIdx.x * 2048;
  #pragma unroll
  for (int i = 0; i < 8; ++i) {
    const int e = e0 + t + i * 256;
    if (e < E_EDGES) {
      const int s = is64 ? ((const int4*)edges)[e].x : ((const int2*)edges)[e].x;
      atomicAdd(&lh[s >> BKT_SHIFT], 1);
    }
  }
  __syncthreads();
  for (int j = t; j < NBKT; j += 256)
    if (lh[j]) atomicAdd(&bcnt[j], lh[j]);
}

// ---------------- K2: exclusive scan of bucket counts (single block) ----------------
__global__ __launch_bounds__(1024) void bucket_scan_kernel(const int* __restrict__ bcnt,
                                                           int* __restrict__ bbase,
                                                           int* __restrict__ bcur) {
  __shared__ int buf[1024];
  const int t = threadIdx.x;
  const int v = (t < NBKT) ? bcnt[t] : 0;
  buf[t] = v;
  __syncthreads();
  for (int o = 1; o < 1024; o <<= 1) {
    int add = (t >= o) ? buf[t - o] : 0;
    __syncthreads();
    buf[t] += add;
    __syncthreads();
  }
  if (t < NBKT) {
    const int ex = buf[t] - v;
    bbase[t] = ex;
    bcur[t]  = ex;
  }
  if (t == 0) bbase[NBKT] = E_EDGES;
}

// ---------------- K3: bucket scatter (single pass, edges cached in VGPRs) ----------------
__global__ __launch_bounds__(SC_BLOCK) void bucket_scatter_kernel(
    const int* __restrict__ edges, int* __restrict__ bcur,
    int2* __restrict__ pairs, const int* __restrict__ flag)
{
  __shared__ int lh[NBKT];
  __shared__ int lbase[NBKT];
  const int t = threadIdx.x;
  for (int j = t; j < NBKT; j += SC_BLOCK) lh[j] = 0;
  __syncthreads();

  const int is64 = *flag;
  const int e0 = blockIdx.x * SC_EDGES;
  int ss[SC_EPT], dd[SC_EPT];
  #pragma unroll
  for (int i = 0; i < SC_EPT; ++i) {
    const int e = e0 + t + i * SC_BLOCK;
    int s = -1, d = 0;
    if (e < E_EDGES) {
      if (is64) { int4 v = ((const int4*)edges)[e]; s = v.x; d = v.z; }
      else      { int2 v = ((const int2*)edges)[e]; s = v.x; d = v.y; }
      atomicAdd(&lh[s >> BKT_SHIFT], 1);
    }
    ss[i] = s; dd[i] = d;
  }
  __syncthreads();
  for (int j = t; j < NBKT; j += SC_BLOCK) {
    const int c = lh[j];
    lbase[j] = c ? atomicAdd(&bcur[j], c) : 0;
  }
  __syncthreads();
  for (int j = t; j < NBKT; j += SC_BLOCK) lh[j] = 0;
  __syncthreads();
  #pragma unroll
  for (int i = 0; i < SC_EPT; ++i) {
    const int s = ss[i];
    if (s >= 0) {
      const int b = s >> BKT_SHIFT;
      const int pos = lbase[b] + atomicAdd(&lh[b], 1);
      pairs[pos] = make_int2(s, dd[i]);
    }
  }
}

// ---------------- K4: per-bucket counting sort + weight precompute (in place) --------
__global__ __launch_bounds__(256) void bucket_sort_kernel(
    const float* __restrict__ s1, const float* __restrict__ s2,
    const int* __restrict__ bbase, int2* __restrict__ pairs, int* __restrict__ off)
{
  __shared__ int2  lp[BUCKET_CAP];
  __shared__ int   hist[BKT_NODES];
  __shared__ int   loff[BKT_NODES];
  __shared__ float ls1[BKT_NODES];
  const int b = blockIdx.x, t = threadIdx.x;
  const int nbase = b << BKT_SHIFT;
  const int nn = min(BKT_NODES, N_NODES - nbase);
  const int beg = bbase[b], end = bbase[b + 1];
  const int cnt = min(end - beg, BUCKET_CAP);

  if (t < BKT_NODES) {
    hist[t] = 0;
    if (t < nn) ls1[t] = s1[nbase + t];
  }
  __syncthreads();
  for (int j = t; j < cnt; j += 256) {
    const int2 p = pairs[beg + j];
    lp[j] = p;
    atomicAdd(&hist[p.x - nbase], 1);
  }
  __syncthreads();
  if (t < BKT_NODES) loff[t] = hist[t];
  __syncthreads();
  for (int o = 1; o < BKT_NODES; o <<= 1) {
    int add = 0;
    if (t < BKT_NODES && t >= o) add = loff[t - o];
    __syncthreads();
    if (t < BKT_NODES) loff[t] += add;
    __syncthreads();
  }
  int excl = 0;
  if (t < BKT_NODES) {
    excl = loff[t] - hist[t];
    if (t < nn) off[nbase + t] = beg + excl;
  }
  if (b == NBKT - 1 && t == 0) off[N_NODES] = E_EDGES;
  __syncthreads();
  if (t < BKT_NODES) { loff[t] = excl; hist[t] = 0; }
  __syncthreads();
  for (int j = t; j < cnt; j += 256) {
    const int2 p = lp[j];
    const int li = p.x - nbase;
    const int pos = beg + loff[li] + atomicAdd(&hist[li], 1);
    const float lg = ls1[li] + s2[p.y];
    const float w = __expf(lg >= 0.f ? lg : SLOPE * lg);
    pairs[pos] = make_int2(p.y, __float_as_int(w));
  }
}

// ---------------- K5: one wave per node, lane = output dim ----------------
__global__ __launch_bounds__(256) void aggregate_kernel(
    const float* __restrict__ emb, const float* __restrict__ s1, const float* __restrict__ s2,
    const int* __restrict__ off, const int2* __restrict__ pairs, float* __restrict__ out)
{
  const int lane = threadIdx.x & 63;
  const int node = blockIdx.x * 4 + (threadIdx.x >> 6);
  if (node >= N_NODES) return;

  const float esel = emb[(size_t)node * OUT_DIM + lane];
  const float lg = s1[node] + s2[node];
  const float wself = __expf(lg >= 0.f ? lg : SLOPE * lg);
  float acc0 = wself * esel, acc1 = 0.f, acc2 = 0.f, acc3 = 0.f;
  float wsum = wself;

  const int beg = off[node], end = off[node + 1];
  for (int j0 = beg; j0 < end; j0 += 64) {
    int dj = 0; float wj = 0.f;
    if (j0 + lane < end) {
      const int2 p = pairs[j0 + lane];
      dj = p.x;
      wj = __int_as_float(p.y);
    }
    const int m = min(64, end - j0);
    int q = 0;
    for (; q + 4 <= m; q += 4) {
      const int   d0 = __shfl(dj, q, 64),     d1 = __shfl(dj, q + 1, 64);
      const int   d2 = __shfl(dj, q + 2, 64), d3 = __shfl(dj, q + 3, 64);
      const float w0 = __shfl(wj, q, 64),     w1 = __shfl(wj, q + 1, 64);
      const float w2 = __shfl(wj, q + 2, 64), w3 = __shfl(wj, q + 3, 64);
      const float e0 = emb[(size_t)d0 * OUT_DIM + lane];
      const float e1 = emb[(size_t)d1 * OUT_DIM + lane];
      const float e2 = emb[(size_t)d2 * OUT_DIM + lane];
      const float e3 = emb[(size_t)d3 * OUT_DIM + lane];
      acc0 += w0 * e0; acc1 += w1 * e1; acc2 += w2 * e2; acc3 += w3 * e3;
      wsum += w0 + w1 + w2 + w3;
    }
    for (; q < m; ++q) {
      const int   d = __shfl(dj, q, 64);
      const float w = __shfl(wj, q, 64);
      acc0 += w * emb[(size_t)d * OUT_DIM + lane];
      wsum += w;
    }
  }
  out[(size_t)node * OUT_DIM + lane] = (acc0 + acc1 + acc2 + acc3) / wsum;
}

extern "C" void kernel_launch(void* const* d_in, const int* in_sizes, int n_in,
                              void* d_out, int out_size, void* d_ws, size_t ws_size,
                              hipStream_t stream) {
  const float* features = (const float*)d_in[0];
  const float* W        = (const float*)d_in[1];
  const float* b        = (const float*)d_in[2];
  const float* a        = (const float*)d_in[3];
  const int*   edges    = (const int*)d_in[4];
  float* out = (float*)d_out;

  // workspace layout (4B units)
  float* emb   = (float*)d_ws;                       // N*64
  float* s1    = emb + (size_t)N_NODES * OUT_DIM;    // N
  float* s2    = s1 + N_NODES;                       // N
  int*   off   = (int*)(s2 + N_NODES);               // N+1
  int*   bcnt  = off + N_NODES + 1;                  // NBKT
  int*   bbase = bcnt + NBKT;                        // NBKT+1
  int*   bcur  = bbase + NBKT + 1;                   // NBKT
  int*   flag  = bcur + NBKT;                        // 1 (+pad)
  int2*  pairs = (int2*)(flag + 8);                  // E (8B each)

  hipLaunchKernelGGL(zero_detect_kernel, dim3((NBKT + 255) / 256), dim3(256), 0, stream,
                     bcnt, edges, flag);
  hipLaunchKernelGGL(embed_kernel, dim3(NBKT), dim3(256), 0, stream,
                     features, W, b, a, emb, s1, s2, edges, flag, bcnt);
  hipLaunchKernelGGL(bucket_scan_kernel, dim3(1), dim3(1024), 0, stream,
                     bcnt, bbase, bcur);
  hipLaunchKernelGGL(bucket_scatter_kernel, dim3(SC_GRID), dim3(SC_BLOCK), 0, stream,
                     edges, bcur, pairs, flag);
  hipLaunchKernelGGL(bucket_sort_kernel, dim3(NBKT), dim3(256), 0, stream,
                     s1, s2, bbase, pairs, off);
  hipLaunchKernelGGL(aggregate_kernel, dim3((N_NODES + 3) / 4), dim3(256), 0, stream,
                     emb, s1, s2, off, pairs, out);
}

// Round 5
// 168.708 us; speedup vs baseline: 2.7696x; 1.0601x over previous
//
#include <hip/hip_runtime.h>

#define N_NODES 100000
#define E_EDGES 1600000
#define IN_DIM  256
#define OUT_DIM 64
#define SLOPE   0.1f

#define BKT_SHIFT  7
#define BKT_NODES  128
#define NBKT       ((N_NODES + BKT_NODES - 1) / BKT_NODES)   // 782
#define BUCKET_CAP 3072
#define SC_BLOCK   1024
#define SC_EPT     16
#define SC_EDGES   (SC_BLOCK * SC_EPT)                        // 16384
#define SC_GRID    ((E_EDGES + SC_EDGES - 1) / SC_EDGES)      // 98

typedef __attribute__((ext_vector_type(8))) short bhalf8;
typedef __attribute__((ext_vector_type(4))) float f32x4;

__device__ __forceinline__ unsigned short f2bf(float x) {
  unsigned u = __float_as_uint(x);
  u = (u + 0x7fffu + ((u >> 16) & 1u)) >> 16;   // RNE
  return (unsigned short)u;
}

// ---------------- K0: zero bucket counters + detect int32/int64 edge layout ----------------
__global__ void zero_detect_kernel(int* __restrict__ bcnt, const int* __restrict__ edges,
                                   int* __restrict__ flag) {
  int i = blockIdx.x * blockDim.x + threadIdx.x;
  if (i < NBKT) bcnt[i] = 0;
  if (i == 0) {
    int all0 = 1;
    for (int j = 0; j < 64; ++j)
      if (edges[2 * j + 1] != 0) all0 = 0;
    *flag = all0;  // 1 => int64 layout (high dwords zero), 0 => int32
  }
}

// ---------------- K1: emb = bf16(X@W^T)+b via MFMA; A direct global->reg, W in LDS ------
// 782 blocks x 256 thr (4 waves). LDS = W 32KB + hist 3.1KB -> 4 blocks/CU; no barrier
// in the K-loop (each wave owns its 32 rows; A fragments loaded straight from global).
__global__ __launch_bounds__(256) void embed_kernel(
    const float* __restrict__ features, const float* __restrict__ W,
    const float* __restrict__ bias, const float* __restrict__ a,
    float* __restrict__ emb, float* __restrict__ s1, float* __restrict__ s2,
    const int* __restrict__ edges, const int* __restrict__ flag, int* __restrict__ bcnt)
{
  __shared__ short Wlds[64 * 256];    // 32 KB, col stride 512 B, byte^((col&7)<<4)
  __shared__ int   lh[NBKT];          // 3.1 KB (bucket histogram)

  const int t = threadIdx.x;
  const int w = t >> 6;
  const int l = t & 63;
  const int lg = l >> 4;      // 0..3  (k-chunk group)
  const int lr = l & 15;      // 0..15 (row/col within tile)
  const int row0 = blockIdx.x * 128;

  // ---- stage W: thread t -> col=t>>2, k-quarter=(t&3)*64 floats ----
  {
    const int col = t >> 2;
    const int kq  = (t & 3) * 64;
    const float* src = &W[(size_t)col * IN_DIM + kq];
    char* dstbase = (char*)Wlds + col * 512;
    #pragma unroll
    for (int j = 0; j < 8; ++j) {
      const float4 f0 = *(const float4*)&src[j * 8];
      const float4 f1 = *(const float4*)&src[j * 8 + 4];
      bhalf8 v;
      v[0] = f2bf(f0.x); v[1] = f2bf(f0.y); v[2] = f2bf(f0.z); v[3] = f2bf(f0.w);
      v[4] = f2bf(f1.x); v[5] = f2bf(f1.y); v[6] = f2bf(f1.z); v[7] = f2bf(f1.w);
      *(bhalf8*)(dstbase + (((kq * 2 + j * 16)) ^ ((col & 7) << 4))) = v;
    }
  }
  __syncthreads();

  // ---- acc init with bias ----
  float bc[4];
  #pragma unroll
  for (int ct = 0; ct < 4; ++ct) bc[ct] = bias[ct * 16 + lr];
  f32x4 acc[2][4];
  #pragma unroll
  for (int rt = 0; rt < 2; ++rt)
    #pragma unroll
    for (int ct = 0; ct < 4; ++ct) {
      acc[rt][ct][0] = bc[ct]; acc[rt][ct][1] = bc[ct];
      acc[rt][ct][2] = bc[ct]; acc[rt][ct][3] = bc[ct];
    }

  // ---- A fragment base pointers (lane-private rows, clamped for tail block) ----
  const float* arow[2];
  #pragma unroll
  for (int rt = 0; rt < 2; ++rt) {
    const int rowc = min(row0 + w * 32 + rt * 16 + lr, N_NODES - 1);
    arow[rt] = &features[(size_t)rowc * IN_DIM + lg * 8];
  }

  // 2-deep pipeline: raw f32 for current ks in regs, prefetch next while MFMA runs
  float4 ra0[2], ra1[2];
  #pragma unroll
  for (int rt = 0; rt < 2; ++rt) {
    ra0[rt] = *(const float4*)(arow[rt]);
    ra1[rt] = *(const float4*)(arow[rt] + 4);
  }

  const int ksw = (lr & 7) << 4;
  #pragma unroll
  for (int ks = 0; ks < 8; ++ks) {
    bhalf8 af[2];
    #pragma unroll
    for (int rt = 0; rt < 2; ++rt) {
      af[rt][0] = f2bf(ra0[rt].x); af[rt][1] = f2bf(ra0[rt].y);
      af[rt][2] = f2bf(ra0[rt].z); af[rt][3] = f2bf(ra0[rt].w);
      af[rt][4] = f2bf(ra1[rt].x); af[rt][5] = f2bf(ra1[rt].y);
      af[rt][6] = f2bf(ra1[rt].z); af[rt][7] = f2bf(ra1[rt].w);
    }
    if (ks < 7) {
      #pragma unroll
      for (int rt = 0; rt < 2; ++rt) {
        ra0[rt] = *(const float4*)(arow[rt] + (ks + 1) * 32);
        ra1[rt] = *(const float4*)(arow[rt] + (ks + 1) * 32 + 4);
      }
    }
    bhalf8 bf[4];
    #pragma unroll
    for (int ct = 0; ct < 4; ++ct) {
      const int col_l = ct * 16 + lr;
      bf[ct] = *(const bhalf8*)((const char*)Wlds + col_l * 512 + ((lg * 16 + ks * 64) ^ ksw));
    }
    #pragma unroll
    for (int rt = 0; rt < 2; ++rt)
      #pragma unroll
      for (int ct = 0; ct < 4; ++ct)
        acc[rt][ct] = __builtin_amdgcn_mfma_f32_16x16x32_bf16(af[rt], bf[ct], acc[rt][ct], 0, 0, 0);
  }

  // ---- epilogue: emb writes + fused s1/s2 (row dots with a1,a2) ----
  float a1c[4], a2c[4];
  #pragma unroll
  for (int ct = 0; ct < 4; ++ct) {
    a1c[ct] = a[ct * 16 + lr];
    a2c[ct] = a[OUT_DIM + ct * 16 + lr];
  }
  #pragma unroll
  for (int rt = 0; rt < 2; ++rt) {
    #pragma unroll
    for (int i = 0; i < 4; ++i) {
      const int row = row0 + w * 32 + rt * 16 + lg * 4 + i;
      float p1 = 0.f, p2 = 0.f;
      #pragma unroll
      for (int ct = 0; ct < 4; ++ct) {
        const float e = acc[rt][ct][i];
        p1 += e * a1c[ct];
        p2 += e * a2c[ct];
        if (row < N_NODES) emb[(size_t)row * OUT_DIM + ct * 16 + lr] = e;
      }
      #pragma unroll
      for (int o = 1; o < 16; o <<= 1) {
        p1 += __shfl_xor(p1, o, 64);
        p2 += __shfl_xor(p2, o, 64);
      }
      if (lr == 0 && row < N_NODES) { s1[row] = p1; s2[row] = p2; }
    }
  }

  // ---- fused bucket histogram over this block's 2048-edge chunk ----
  for (int j = t; j < NBKT; j += 256) lh[j] = 0;
  __syncthreads();
  const int is64 = *flag;
  const int e0 = blockIdx.x * 2048;
  #pragma unroll
  for (int i = 0; i < 8; ++i) {
    const int e = e0 + t + i * 256;
    if (e < E_EDGES) {
      const int s = is64 ? ((const int4*)edges)[e].x : ((const int2*)edges)[e].x;
      atomicAdd(&lh[s >> BKT_SHIFT], 1);
    }
  }
  __syncthreads();
  for (int j = t; j < NBKT; j += 256)
    if (lh[j]) atomicAdd(&bcnt[j], lh[j]);
}

// ---------------- K2: exclusive scan of bucket counts (single block) ----------------
__global__ __launch_bounds__(1024) void bucket_scan_kernel(const int* __restrict__ bcnt,
                                                           int* __restrict__ bbase,
                                                           int* __restrict__ bcur) {
  __shared__ int buf[1024];
  const int t = threadIdx.x;
  const int v = (t < NBKT) ? bcnt[t] : 0;
  buf[t] = v;
  __syncthreads();
  for (int o = 1; o < 1024; o <<= 1) {
    int add = (t >= o) ? buf[t - o] : 0;
    __syncthreads();
    buf[t] += add;
    __syncthreads();
  }
  if (t < NBKT) {
    const int ex = buf[t] - v;
    bbase[t] = ex;
    bcur[t]  = ex;
  }
  if (t == 0) bbase[NBKT] = E_EDGES;
}

// ---------------- K3: bucket scatter (single pass, edges cached in VGPRs) ----------------
__global__ __launch_bounds__(SC_BLOCK) void bucket_scatter_kernel(
    const int* __restrict__ edges, int* __restrict__ bcur,
    int2* __restrict__ pairs, const int* __restrict__ flag)
{
  __shared__ int lh[NBKT];
  __shared__ int lbase[NBKT];
  const int t = threadIdx.x;
  for (int j = t; j < NBKT; j += SC_BLOCK) lh[j] = 0;
  __syncthreads();

  const int is64 = *flag;
  const int e0 = blockIdx.x * SC_EDGES;
  int ss[SC_EPT], dd[SC_EPT];
  #pragma unroll
  for (int i = 0; i < SC_EPT; ++i) {
    const int e = e0 + t + i * SC_BLOCK;
    int s = -1, d = 0;
    if (e < E_EDGES) {
      if (is64) { int4 v = ((const int4*)edges)[e]; s = v.x; d = v.z; }
      else      { int2 v = ((const int2*)edges)[e]; s = v.x; d = v.y; }
      atomicAdd(&lh[s >> BKT_SHIFT], 1);
    }
    ss[i] = s; dd[i] = d;
  }
  __syncthreads();
  for (int j = t; j < NBKT; j += SC_BLOCK) {
    const int c = lh[j];
    lbase[j] = c ? atomicAdd(&bcur[j], c) : 0;
  }
  __syncthreads();
  for (int j = t; j < NBKT; j += SC_BLOCK) lh[j] = 0;
  __syncthreads();
  #pragma unroll
  for (int i = 0; i < SC_EPT; ++i) {
    const int s = ss[i];
    if (s >= 0) {
      const int b = s >> BKT_SHIFT;
      const int pos = lbase[b] + atomicAdd(&lh[b], 1);
      pairs[pos] = make_int2(s, dd[i]);
    }
  }
}

// ---------------- K4: per-bucket counting sort + weight precompute (in place) --------
__global__ __launch_bounds__(256) void bucket_sort_kernel(
    const float* __restrict__ s1, const float* __restrict__ s2,
    const int* __restrict__ bbase, int2* __restrict__ pairs, int* __restrict__ off)
{
  __shared__ int2  lp[BUCKET_CAP];
  __shared__ int   hist[BKT_NODES];
  __shared__ int   loff[BKT_NODES];
  __shared__ float ls1[BKT_NODES];
  const int b = blockIdx.x, t = threadIdx.x;
  const int nbase = b << BKT_SHIFT;
  const int nn = min(BKT_NODES, N_NODES - nbase);
  const int beg = bbase[b], end = bbase[b + 1];
  const int cnt = min(end - beg, BUCKET_CAP);

  if (t < BKT_NODES) {
    hist[t] = 0;
    if (t < nn) ls1[t] = s1[nbase + t];
  }
  __syncthreads();
  for (int j = t; j < cnt; j += 256) {
    const int2 p = pairs[beg + j];
    lp[j] = p;
    atomicAdd(&hist[p.x - nbase], 1);
  }
  __syncthreads();
  if (t < BKT_NODES) loff[t] = hist[t];
  __syncthreads();
  for (int o = 1; o < BKT_NODES; o <<= 1) {
    int add = 0;
    if (t < BKT_NODES && t >= o) add = loff[t - o];
    __syncthreads();
    if (t < BKT_NODES) loff[t] += add;
    __syncthreads();
  }
  int excl = 0;
  if (t < BKT_NODES) {
    excl = loff[t] - hist[t];
    if (t < nn) off[nbase + t] = beg + excl;
  }
  if (b == NBKT - 1 && t == 0) off[N_NODES] = E_EDGES;
  __syncthreads();
  if (t < BKT_NODES) { loff[t] = excl; hist[t] = 0; }
  __syncthreads();
  for (int j = t; j < cnt; j += 256) {
    const int2 p = lp[j];
    const int li = p.x - nbase;
    const int pos = beg + loff[li] + atomicAdd(&hist[li], 1);
    const float lg = ls1[li] + s2[p.y];
    const float w = __expf(lg >= 0.f ? lg : SLOPE * lg);
    pairs[pos] = make_int2(p.y, __float_as_int(w));
  }
}

// ---------------- K5: one wave per node, lane = output dim ----------------
__global__ __launch_bounds__(256) void aggregate_kernel(
    const float* __restrict__ emb, const float* __restrict__ s1, const float* __restrict__ s2,
    const int* __restrict__ off, const int2* __restrict__ pairs, float* __restrict__ out)
{
  const int lane = threadIdx.x & 63;
  const int node = blockIdx.x * 4 + (threadIdx.x >> 6);
  if (node >= N_NODES) return;

  const float esel = emb[(size_t)node * OUT_DIM + lane];
  const float lg = s1[node] + s2[node];
  const float wself = __expf(lg >= 0.f ? lg : SLOPE * lg);
  float acc0 = wself * esel, acc1 = 0.f, acc2 = 0.f, acc3 = 0.f;
  float wsum = wself;

  const int beg = off[node], end = off[node + 1];
  for (int j0 = beg; j0 < end; j0 += 64) {
    int dj = 0; float wj = 0.f;
    if (j0 + lane < end) {
      const int2 p = pairs[j0 + lane];
      dj = p.x;
      wj = __int_as_float(p.y);
    }
    const int m = min(64, end - j0);
    int q = 0;
    for (; q + 4 <= m; q += 4) {
      const int   d0 = __shfl(dj, q, 64),     d1 = __shfl(dj, q + 1, 64);
      const int   d2 = __shfl(dj, q + 2, 64), d3 = __shfl(dj, q + 3, 64);
      const float w0 = __shfl(wj, q, 64),     w1 = __shfl(wj, q + 1, 64);
      const float w2 = __shfl(wj, q + 2, 64), w3 = __shfl(wj, q + 3, 64);
      const float e0 = emb[(size_t)d0 * OUT_DIM + lane];
      const float e1 = emb[(size_t)d1 * OUT_DIM + lane];
      const float e2 = emb[(size_t)d2 * OUT_DIM + lane];
      const float e3 = emb[(size_t)d3 * OUT_DIM + lane];
      acc0 += w0 * e0; acc1 += w1 * e1; acc2 += w2 * e2; acc3 += w3 * e3;
      wsum += w0 + w1 + w2 + w3;
    }
    for (; q < m; ++q) {
      const int   d = __shfl(dj, q, 64);
      const float w = __shfl(wj, q, 64);
      acc0 += w * emb[(size_t)d * OUT_DIM + lane];
      wsum += w;
    }
  }
  out[(size_t)node * OUT_DIM + lane] = (acc0 + acc1 + acc2 + acc3) / wsum;
}

extern "C" void kernel_launch(void* const* d_in, const int* in_sizes, int n_in,
                              void* d_out, int out_size, void* d_ws, size_t ws_size,
                              hipStream_t stream) {
  const float* features = (const float*)d_in[0];
  const float* W        = (const float*)d_in[1];
  const float* b        = (const float*)d_in[2];
  const float* a        = (const float*)d_in[3];
  const int*   edges    = (const int*)d_in[4];
  float* out = (float*)d_out;

  // workspace layout (4B units)
  float* emb   = (float*)d_ws;                       // N*64
  float* s1    = emb + (size_t)N_NODES * OUT_DIM;    // N
  float* s2    = s1 + N_NODES;                       // N
  int*   off   = (int*)(s2 + N_NODES);               // N+1
  int*   bcnt  = off + N_NODES + 1;                  // NBKT
  int*   bbase = bcnt + NBKT;                        // NBKT+1
  int*   bcur  = bbase + NBKT + 1;                   // NBKT
  int*   flag  = bcur + NBKT;                        // 1 (+pad)
  int2*  pairs = (int2*)(flag + 8);                  // E (8B each)

  hipLaunchKernelGGL(zero_detect_kernel, dim3((NBKT + 255) / 256), dim3(256), 0, stream,
                     bcnt, edges, flag);
  hipLaunchKernelGGL(embed_kernel, dim3(NBKT), dim3(256), 0, stream,
                     features, W, b, a, emb, s1, s2, edges, flag, bcnt);
  hipLaunchKernelGGL(bucket_scan_kernel, dim3(1), dim3(1024), 0, stream,
                     bcnt, bbase, bcur);
  hipLaunchKernelGGL(bucket_scatter_kernel, dim3(SC_GRID), dim3(SC_BLOCK), 0, stream,
                     edges, bcur, pairs, flag);
  hipLaunchKernelGGL(bucket_sort_kernel, dim3(NBKT), dim3(256), 0, stream,
                     s1, s2, bbase, pairs, off);
  hipLaunchKernelGGL(aggregate_kernel, dim3((N_NODES + 3) / 4), dim3(256), 0, stream,
                     emb, s1, s2, off, pairs, out);
}